// Round 9
// baseline (571.958 us; speedup 1.0000x reference)
//
#include <hip/hip_runtime.h>
#include <stdint.h>

#define NB 64
#define NR 1152
#define NI 64
#define NC 32
#define NO 32

typedef float float8v __attribute__((ext_vector_type(8)));

// ---------------------------------------------------------------------------
// K1: priors[c,b,r,o] = sum_i x[b,r,i] * W[c,r,i,o], fp32.
// grid (NC, NR), block 256 = 4 waves. Wave = o-oct (o = wv*8+q), lane = b.
// W[c,r,i,o-oct*8..+8] is WAVE-UNIFORM -> loaded via the SCALAR pipe
// (s_load_dwordx8 into SGPRs; readfirstlane forces uniformity). SGPR
// broadcast feeds FMA directly (1 scalar operand per VALU instr).
// x read from original [b][r][i] layout, lane=b, float4 per 4-i (L3-resident).
// acc = 8 VGPR -> tiny VGPR footprint, deep 2-stage prefetch in SGPRs.
// Epilogue: LDS transpose (pad 33, conflict-free) -> P stored [c][b][r][o]
// in full 64B lines, matching k_route's proven layout.
// ---------------------------------------------------------------------------
__global__ __launch_bounds__(256, 4)
void k_priors(const float* __restrict__ x, const float* __restrict__ W,
              float* __restrict__ P) {
  __shared__ float tile[NB][NO + 1];   // 64 x 33, +1 pad: conflict-free

  const int tid  = threadIdx.x;
  const int lane = tid & 63;                                   // b
  const int wvu  = __builtin_amdgcn_readfirstlane(tid >> 6);   // o-oct, uniform
  const int c    = blockIdx.x;
  const int r    = blockIdx.y;

  // wave-uniform W pointer: W[c][r][i][wvu*8 + ...]
  const float* Wr = W + ((size_t)c * NR + r) * (NI * NO) + wvu * 8;
  // per-lane x pointer: x[b][r][i]
  const float* xr = x + ((size_t)lane * NR + r) * NI;

  float acc[8];
#pragma unroll
  for (int q = 0; q < 8; ++q) acc[q] = 0.f;

#define WLD(KB, II) (*reinterpret_cast<const float8v*>(Wr + ((KB) * 4 + (II)) * NO))

  // 2-stage pipeline over 16 blocks of 4 i's
  float4  xv = *reinterpret_cast<const float4*>(xr);
  float8v w0 = WLD(0, 0), w1 = WLD(0, 1), w2 = WLD(0, 2), w3 = WLD(0, 3);

#pragma unroll
  for (int kb = 0; kb < 16; ++kb) {
    float4  xn;
    float8v n0, n1, n2, n3;
    if (kb < 15) {
      xn = *reinterpret_cast<const float4*>(xr + (kb + 1) * 4);
      n0 = WLD(kb + 1, 0); n1 = WLD(kb + 1, 1);
      n2 = WLD(kb + 1, 2); n3 = WLD(kb + 1, 3);
    }
    const float xs[4] = {xv.x, xv.y, xv.z, xv.w};
#pragma unroll
    for (int q = 0; q < 8; ++q) acc[q] = fmaf(xs[0], w0[q], acc[q]);
#pragma unroll
    for (int q = 0; q < 8; ++q) acc[q] = fmaf(xs[1], w1[q], acc[q]);
#pragma unroll
    for (int q = 0; q < 8; ++q) acc[q] = fmaf(xs[2], w2[q], acc[q]);
#pragma unroll
    for (int q = 0; q < 8; ++q) acc[q] = fmaf(xs[3], w3[q], acc[q]);
    if (kb < 15) { xv = xn; w0 = n0; w1 = n1; w2 = n2; w3 = n3; }
  }
#undef WLD

  // transpose-store through LDS: tile[b][o]
#pragma unroll
  for (int q = 0; q < 8; ++q) tile[lane][wvu * 8 + q] = acc[q];
  __syncthreads();

  {
    const int sb = tid >> 2;          // b row 0..63
    const int so = (tid & 3) * 8;     // o start 0,8,16,24
    const float4 o0 = make_float4(tile[sb][so + 0], tile[sb][so + 1],
                                  tile[sb][so + 2], tile[sb][so + 3]);
    const float4 o1 = make_float4(tile[sb][so + 4], tile[sb][so + 5],
                                  tile[sb][so + 6], tile[sb][so + 7]);
    float* dst = P + (((size_t)c * NB + sb) * NR + r) * NO + so;
    *reinterpret_cast<float4*>(dst)     = o0;
    *reinterpret_cast<float4*>(dst + 4) = o1;
  }
}

// ---------------------------------------------------------------------------
// K2: full 3-iteration routing for one (c,b). block 1024 (16 waves).
// 8 lanes per route-row (sl = o-slice of 4); P slice in registers p[9],
// read from global exactly once, coalesced 1 KB per wave instruction.
// ---------------------------------------------------------------------------
__device__ __forceinline__ void merge4(float& m, float& Z, float4& T,
                                       float m2, float Z2, const float4& T2) {
  const float mn = fmaxf(m, m2);
  const float a1 = __expf(m - mn), a2 = __expf(m2 - mn);
  Z   = Z * a1 + Z2 * a2;
  T.x = T.x * a1 + T2.x * a2;
  T.y = T.y * a1 + T2.y * a2;
  T.z = T.z * a1 + T2.z * a2;
  T.w = T.w * a1 + T2.w * a2;
  m = mn;
}

__global__ __launch_bounds__(1024, 1)
void k_route(const float* __restrict__ P, float* __restrict__ out) {
  __shared__ float red_s[16][8][8];  // [wave][slice][m,Z,T0..3,pad2]
  __shared__ float u_s[NO];

  const int tid  = threadIdx.x;
  const int lane = tid & 63;
  const int wave = tid >> 6;
  const int sl   = tid & 7;   // o-slice: o = sl*4 + 0..3
  const int grp  = tid >> 3;  // row group 0..127; rows r = grp + 128*j
  const int b    = blockIdx.x;
  const int c    = blockIdx.y;
  const float* Pb = P + ((size_t)c * NB + b) * ((size_t)NR * NO);

  float4 p[9];
#pragma unroll
  for (int j = 0; j < 9; ++j)
    p[j] = *reinterpret_cast<const float4*>(Pb + (size_t)(grp + 128 * j) * NO + sl * 4);

  // ---- iteration 0: uniform softmax -> S0 = mean_r p ----
  {
    float4 T = p[0];
#pragma unroll
    for (int j = 1; j < 9; ++j) {
      T.x += p[j].x; T.y += p[j].y; T.z += p[j].z; T.w += p[j].w;
    }
#pragma unroll
    for (int off = 8; off <= 32; off <<= 1) {
      T.x += __shfl_xor(T.x, off); T.y += __shfl_xor(T.y, off);
      T.z += __shfl_xor(T.z, off); T.w += __shfl_xor(T.w, off);
    }
    if (lane < 8) {
      red_s[wave][sl][2] = T.x; red_s[wave][sl][3] = T.y;
      red_s[wave][sl][4] = T.z; red_s[wave][sl][5] = T.w;
    }
  }
  __syncthreads();
  if (tid < 8) {
    float4 S = make_float4(0.f, 0.f, 0.f, 0.f);
#pragma unroll
    for (int ww = 0; ww < 16; ++ww) {
      S.x += red_s[ww][tid][2]; S.y += red_s[ww][tid][3];
      S.z += red_s[ww][tid][4]; S.w += red_s[ww][tid][5];
    }
    S.x *= (1.f / NR); S.y *= (1.f / NR); S.z *= (1.f / NR); S.w *= (1.f / NR);
    float n2 = S.x * S.x + S.y * S.y + S.z * S.z + S.w * S.w;
    n2 += __shfl_xor(n2, 1); n2 += __shfl_xor(n2, 2); n2 += __shfl_xor(n2, 4);
    const float scale = n2 / ((1.f + n2) * sqrtf(n2));
    u_s[tid * 4 + 0] = S.x * scale; u_s[tid * 4 + 1] = S.y * scale;
    u_s[tid * 4 + 2] = S.z * scale; u_s[tid * 4 + 3] = S.w * scale;
  }
  __syncthreads();

  float4 u = *reinterpret_cast<const float4*>(&u_s[sl * 4]);
  float l1[9];

  for (int it = 1; it <= 2; ++it) {
    float m = -3.0e38f, Z = 0.f;
    float4 T = make_float4(0.f, 0.f, 0.f, 0.f);
#pragma unroll
    for (int j = 0; j < 9; ++j) {
      float d = p[j].x * u.x + p[j].y * u.y + p[j].z * u.z + p[j].w * u.w;
      d += __shfl_xor(d, 1); d += __shfl_xor(d, 2); d += __shfl_xor(d, 4);
      float l;
      if (it == 1) { l1[j] = d; l = d; }
      else         { l = l1[j] + d; }
      const float mn = fmaxf(m, l);
      const float a = __expf(m - mn);
      const float e = __expf(l - mn);
      Z   = Z * a + e;
      T.x = T.x * a + e * p[j].x; T.y = T.y * a + e * p[j].y;
      T.z = T.z * a + e * p[j].z; T.w = T.w * a + e * p[j].w;
      m = mn;
    }
#pragma unroll
    for (int off = 8; off <= 32; off <<= 1) {
      const float m2 = __shfl_xor(m, off);
      const float Z2 = __shfl_xor(Z, off);
      float4 T2;
      T2.x = __shfl_xor(T.x, off); T2.y = __shfl_xor(T.y, off);
      T2.z = __shfl_xor(T.z, off); T2.w = __shfl_xor(T.w, off);
      merge4(m, Z, T, m2, Z2, T2);
    }
    if (lane < 8) {
      red_s[wave][sl][0] = m;   red_s[wave][sl][1] = Z;
      red_s[wave][sl][2] = T.x; red_s[wave][sl][3] = T.y;
      red_s[wave][sl][4] = T.z; red_s[wave][sl][5] = T.w;
    }
    __syncthreads();
    if (tid < 8) {
      float mm = red_s[0][tid][0], ZZ = red_s[0][tid][1];
      float4 TT = make_float4(red_s[0][tid][2], red_s[0][tid][3],
                              red_s[0][tid][4], red_s[0][tid][5]);
#pragma unroll
      for (int ww = 1; ww < 16; ++ww) {
        const float4 T2 = make_float4(red_s[ww][tid][2], red_s[ww][tid][3],
                                      red_s[ww][tid][4], red_s[ww][tid][5]);
        merge4(mm, ZZ, TT, red_s[ww][tid][0], red_s[ww][tid][1], T2);
      }
      const float inv = 1.f / ZZ;
      float4 S = make_float4(TT.x * inv, TT.y * inv, TT.z * inv, TT.w * inv);
      float n2 = S.x * S.x + S.y * S.y + S.z * S.z + S.w * S.w;
      n2 += __shfl_xor(n2, 1); n2 += __shfl_xor(n2, 2); n2 += __shfl_xor(n2, 4);
      const float scale = n2 / ((1.f + n2) * sqrtf(n2));
      if (it == 1) {
        u_s[tid * 4 + 0] = S.x * scale; u_s[tid * 4 + 1] = S.y * scale;
        u_s[tid * 4 + 2] = S.z * scale; u_s[tid * 4 + 3] = S.w * scale;
      } else {
        *reinterpret_cast<float4*>(out + ((size_t)b * NC + c) * NO + tid * 4) =
            make_float4(S.x * scale, S.y * scale, S.z * scale, S.w * scale);
      }
    }
    __syncthreads();
    if (it == 1) u = *reinterpret_cast<const float4*>(&u_s[sl * 4]);
  }
}

extern "C" void kernel_launch(void* const* d_in, const int* in_sizes, int n_in,
                              void* d_out, int out_size, void* d_ws, size_t ws_size,
                              hipStream_t stream) {
  const float* x = (const float*)d_in[0];
  // d_in[1] (cond) is unused by the reference computation
  const float* W = (const float*)d_in[2];
  float* out = (float*)d_out;
  float* P = (float*)d_ws;                        // 302 MB priors

  k_priors<<<dim3(NC, NR), 256, 0, stream>>>(x, W, P);
  k_route<<<dim3(NB, NC), 1024, 0, stream>>>(P, out);
}